// Round 7
// baseline (47.914 us; speedup 1.0000x reference)
//
#include <hip/hip_runtime.h>

// ExplicitLiePE via MFMA: y[b,s] = expm(A) @ x[b,s], A = sum_k r_k * 0.5*(L_k - L_k^T).
//
// Round-6 (16-token groups, 4 waves/block row-split, dbuf LDS exchange) hit
// ~27us main kernel at 2 waves/SIMD: per-step issue ~250cyc vs ~690cyc elapsed
// -> ~60% latency stall on the serial chain (renorm -> pkrtz -> ds_write ->
// barrier -> ds_read(~120cyc) -> MFMA chains -> update), with only 2 waves/SIMD
// to cover it.
//
// Round-7: 8-token groups. Same 4-wave row-split structure, but grid doubles to
// 1024 blocks -> 4 blocks/CU -> 4 waves/SIMD. Per-wave per-step cost is
// UNCHANGED (18 MFMA, same VALU, same DS); B columns 8..15 duplicate columns
// 0..7 (matrix pipe is ~13% utilized -- the waste is free), so total issue
// doubles but 4 independent chains/SIMD hide the chain latency.
//   - lanes c and c+8 process the SAME token: staging read uses (c&7);
//     stage-writes and out-stores gated to c<8. Per-token arithmetic is
//     bit-identical to round 6 (absmax must stay 0.015625).
//   - amdgpu_waves_per_eu(4) pins VGPR<=128 for 4 waves/SIMD; demand ~110
//     (12 half8 A-frags=48 + state/temps) -> no spill expected. Watch
//     FETCH_SIZE: if it explodes, this attribute caused spill (round-1 lesson).
//
// Math (unchanged): 8 tokens/block advance in lockstep;
//   G_k = (L_k - L_k^T).B, t[:,c] = sum_k (r_k[c]/rho_c) G_k[:,c]
// via v_mfma_f32_16x16x32_f16 with f16 hi/lo split of both L' and b
// (Lhi.bhi + Lhi.blo + Llo.bhi, dropped term ~2^-24). Miller's unnormalized
// scale tamed by per-step renorm s = jc>1 ? rcp(jc) : 1 (result is
// scale-invariant). Per-token seeding at m==ms, coeff gated by m<=M.
//
// Layouts:
//  - C/D: reg r of lane l = D[16*w + (l>>4)*4 + r][l&15] (HW-verified m89/m91).
//  - A/B k-slot bijection k = 8*(l>>4)+j within each K=32 tile.
//  - staging: stage[buf][hi/lo][token ct][dword]; token stride 36 dwords.

typedef _Float16 half8 __attribute__((ext_vector_type(8)));
typedef __fp16 fp16x2 __attribute__((ext_vector_type(2)));
typedef float float4t __attribute__((ext_vector_type(4)));

union H2U { fp16x2 h; unsigned u; };

__device__ __forceinline__ unsigned pkrtz2(float a, float b) {
    H2U v; v.h = __builtin_amdgcn_cvt_pkrtz(a, b); return v.u;
}
__device__ __forceinline__ float h2lo(unsigned u) { H2U v; v.u = u; return (float)v.h[0]; }
__device__ __forceinline__ float h2hi(unsigned u) { H2U v; v.u = u; return (float)v.h[1]; }

// ---------------- prepass: skew-symmetrize + f16 hi/lo split into fragments ----
// ws layout (f16): hi at [f*512 + l*8 + j], lo at +12288, f = (gen*4+m2)*2+kt.
// Fragment element (l, j) of tile (gen, m2, kt) = L'[16m2 + (l&15)][32kt + 8*(l>>4) + j].
__global__ void liepe_prep(const float* __restrict__ L, _Float16* __restrict__ wsA)
{
    int t = blockIdx.x * 256 + threadIdx.x;
    if (t >= 1536) return;
    int l   = t & 63;
    int f   = t >> 6;
    int kt  = f & 1;
    int m   = (f >> 1) & 3;
    int gen = f >> 3;
    int i   = 16 * m + (l & 15);
    int kk0 = 32 * kt + 8 * (l >> 4);
    const float* Lg = L + gen * 4096;
    half8 hi, lo;
    #pragma unroll
    for (int j = 0; j < 8; ++j) {
        int kk = kk0 + j;
        float d = Lg[i * 64 + kk] - Lg[kk * 64 + i];
        _Float16 h = (_Float16)d;
        hi[j] = h;
        lo[j] = (_Float16)(d - (float)h);
    }
    *(half8*)(wsA + f * 512 + l * 8) = hi;
    *(half8*)(wsA + 12288 + f * 512 + l * 8) = lo;
}

// ---------------- main kernel: 4 waves per block, 8 tokens per block ---------

#define PSTR 36   // token stride in dwords (b128-aligned reads)

// stage own b1 slice (hi/lo f16, lanes c<8 only), sync, load B frags, flip buf.
#define STAGE_AND_LOAD_B()                                                       \
  {                                                                              \
    if (c < 8) {                                                                 \
      unsigned h0 = pkrtz2(b1[0], b1[1]);                                        \
      unsigned h1 = pkrtz2(b1[2], b1[3]);                                        \
      unsigned l0 = pkrtz2(b1[0] - h2lo(h0), b1[1] - h2hi(h0));                  \
      unsigned l1 = pkrtz2(b1[2] - h2lo(h1), b1[3] - h2hi(h1));                  \
      const int di = 8 * w + 2 * g;                                              \
      *(uint2*)&stage[buf][0][c][di] = make_uint2(h0, h1);                       \
      *(uint2*)&stage[buf][1][c][di] = make_uint2(l0, l1);                       \
    }                                                                            \
    __syncthreads();                                                             \
    _Pragma("unroll")                                                            \
    for (int kt = 0; kt < 2; ++kt) {                                             \
      Bh[kt] = *(const half8*)&stage[buf][0][ct][16 * kt + 4 * g];               \
      Bl[kt] = *(const half8*)&stage[buf][1][ct][16 * kt + 4 * g];               \
    }                                                                            \
    buf ^= 1;                                                                    \
  }

// 18 MFMAs for this wave's 16-row tile; kt-split accumulators (6 short chains).
#define GEMM_COMBINE(TOUT)                                                       \
  {                                                                              \
    _Pragma("unroll")                                                            \
    for (int gen = 0; gen < 3; ++gen) {                                          \
      float q = (gen == 0) ? q0 : ((gen == 1) ? q1 : q2);                        \
      float4t ac0 = {0.f, 0.f, 0.f, 0.f};                                        \
      float4t ac1 = {0.f, 0.f, 0.f, 0.f};                                        \
      ac0 = __builtin_amdgcn_mfma_f32_16x16x32_f16(Ah[gen*2+0], Bh[0], ac0, 0, 0, 0); \
      ac1 = __builtin_amdgcn_mfma_f32_16x16x32_f16(Ah[gen*2+1], Bh[1], ac1, 0, 0, 0); \
      ac0 = __builtin_amdgcn_mfma_f32_16x16x32_f16(Ah[gen*2+0], Bl[0], ac0, 0, 0, 0); \
      ac1 = __builtin_amdgcn_mfma_f32_16x16x32_f16(Ah[gen*2+1], Bl[1], ac1, 0, 0, 0); \
      ac0 = __builtin_amdgcn_mfma_f32_16x16x32_f16(Al[gen*2+0], Bh[0], ac0, 0, 0, 0); \
      ac1 = __builtin_amdgcn_mfma_f32_16x16x32_f16(Al[gen*2+1], Bh[1], ac1, 0, 0, 0); \
      _Pragma("unroll")                                                          \
      for (int r4 = 0; r4 < 4; ++r4) {                                           \
        float sum = ac0[r4] + ac1[r4];                                           \
        if (gen == 0) TOUT[r4] = q * sum;                                        \
        else          TOUT[r4] = fmaf(q, sum, TOUT[r4]);                         \
      }                                                                          \
    }                                                                            \
  }

__global__ __launch_bounds__(256)
__attribute__((amdgpu_waves_per_eu(4)))
void liepe_mfma(
    const float* __restrict__ x,
    const float* __restrict__ r_grid,
    const _Float16* __restrict__ wsA,
    float* __restrict__ out,
    int n_tokens)
{
    __shared__ __align__(16) unsigned stage[2][2][8][PSTR];  // 9.2KB

    const int lane = threadIdx.x & 63;
    const int w    = threadIdx.x >> 6;   // row-slice / m2 tile, 0..3
    const int c    = lane & 15;          // MFMA column of this lane
    const int ct   = c & 7;              // token index within group (col c and c+8 dup)
    const int g    = lane >> 4;          // k-group / row sub-block

    int tok = blockIdx.x * 8 + ct;
    if (tok >= n_tokens) tok = n_tokens - 1;

    // A-fragments for this wave's row slice (m2 = w): 6 hi + 6 lo (48 VGPRs).
    half8 Ah[6], Al[6];
    #pragma unroll
    for (int gen = 0; gen < 3; ++gen) {
        #pragma unroll
        for (int kt = 0; kt < 2; ++kt) {
            const int f = (gen * 4 + w) * 2 + kt;
            Ah[gen * 2 + kt] = *(const half8*)(wsA + f * 512 + lane * 8);
            Al[gen * 2 + kt] = *(const half8*)(wsA + 12288 + f * 512 + lane * 8);
        }
    }

    // x slice in D-layout: xv[r4] = x[tok][16w + 4g + r4].
    float xv[4];
    {
        float4 v = *(const float4*)(x + tok * 64 + 16 * w + 4 * g);
        xv[0] = v.x; xv[1] = v.y; xv[2] = v.z; xv[3] = v.w;
    }

    // Per-token scalars — identical in all 4 waves (and in lanes c, c+8).
    const float r0 = r_grid[tok * 3 + 0];
    const float r1 = r_grid[tok * 3 + 1];
    const float r2 = r_grid[tok * 3 + 2];
    const float sig2 = 0.5f * (r0 * r0 + r1 * r1 + r2 * r2);
    const float rho  = fmaf(17.3f, __builtin_sqrtf(sig2), 2.0f);
    const float inv_rho = 1.0f / rho;
    const int   M  = (int)rho + 14;     // >= ceil(rho)+13 -> tail ~1e-4
    const int   ms = M + 10;
    const float q0 = r0 * inv_rho, q1 = r1 * inv_rho, q2 = r2 * inv_rho;

    // block max degree (wave-reduce: every wave sees all group tokens).
    int maxM = M;
    #pragma unroll
    for (int off = 1; off < 64; off <<= 1)
        maxM = max(maxM, __shfl_xor(maxM, off));

    float jp = 0.f, jc = 0.f, N = 0.f;
    float b1[4] = {0.f, 0.f, 0.f, 0.f};
    float b2[4] = {0.f, 0.f, 0.f, 0.f};

    // ---- descent: Miller only (all b's exactly 0, no barriers needed) ----
    #pragma unroll 1
    for (int m = maxM + 10; m > maxM; --m) {
        bool sd = (m == ms);
        jc = sd ? 1e-12f : jc;
        jp = sd ? 0.f : jp;
        N  = sd ? (((m & 1) == 0) ? 2e-12f : 0.f) : N;
        float s = (jc > 1.0f) ? __builtin_amdgcn_rcpf(jc) : 1.0f;
        jc *= s; jp *= s; N *= s;
        float jm = fmaf((2.f * (float)m) * inv_rho, jc, -jp);
        jp = jc; jc = jm;
        int mm = m - 1;
        if ((mm & 1) == 0) N += (mm > 0) ? (jm + jm) : jm;
    }

    half8 Bh[2], Bl[2];
    int buf = 0;

    // ---- main fused Miller+Clenshaw loop (1 barrier per step, dbuf) ----
    #pragma unroll 1
    for (int m = maxM; m >= 1; --m) {
        bool sd = (m == ms);
        jc = sd ? 1e-12f : jc;
        jp = sd ? 0.f : jp;
        N  = sd ? (((m & 1) == 0) ? 2e-12f : 0.f) : N;

        // scale-invariant renorm: identical s across waves/dup-lanes
        float s = (jc > 1.0f) ? __builtin_amdgcn_rcpf(jc) : 1.0f;
        jc *= s; jp *= s; N *= s;
        #pragma unroll
        for (int i = 0; i < 4; ++i) { b1[i] *= s; b2[i] *= s; }

        STAGE_AND_LOAD_B();

        float t[4];
        GEMM_COMBINE(t);

        float cf = (m <= M) ? (jc + jc) : 0.f;
        #pragma unroll
        for (int i = 0; i < 4; ++i) {
            float bn = fmaf(cf, xv[i], t[i] + b2[i]);
            b2[i] = b1[i];
            b1[i] = bn;
        }

        float jm = fmaf((2.f * (float)m) * inv_rho, jc, -jp);
        jp = jc; jc = jm;
        int mm = m - 1;
        if ((mm & 1) == 0) N += (mm > 0) ? (jm + jm) : jm;
    }

    // ---- final: b0 = J0*x + (2A/rho)b1 + b2;  y = (b0 - 0.5*(2A/rho)b1)/N ----
    {
        STAGE_AND_LOAD_B();
        float t[4];
        GEMM_COMBINE(t);
        float4 v;
        float y0 = fmaf(jc, xv[0], t[0] + b2[0]);
        float y1 = fmaf(jc, xv[1], t[1] + b2[1]);
        float y2 = fmaf(jc, xv[2], t[2] + b2[2]);
        float y3 = fmaf(jc, xv[3], t[3] + b2[3]);
        v.x = (y0 - 0.5f * t[0]) / N;
        v.y = (y1 - 0.5f * t[1]) / N;
        v.z = (y2 - 0.5f * t[2]) / N;
        v.w = (y3 - 0.5f * t[3]) / N;
        if (c < 8) *(float4*)(out + tok * 64 + 16 * w + 4 * g) = v;
    }
}

extern "C" void kernel_launch(void* const* d_in, const int* in_sizes, int n_in,
                              void* d_out, int out_size, void* d_ws, size_t ws_size,
                              hipStream_t stream) {
    const float* x = (const float*)d_in[0];
    const float* r = (const float*)d_in[1];
    const float* L = (const float*)d_in[2];
    // d_in[3] = P_sp: identity (allow_mixing=False) -> R_eff = R_r.
    float* out = (float*)d_out;
    _Float16* wsA = (_Float16*)d_ws;   // 48KB: 24 hi + 24 lo fragments

    int n_tokens = in_sizes[0] / 64;   // B*S = 8192

    liepe_prep<<<6, 256, 0, stream>>>(L, wsA);

    int nwg = (n_tokens + 7) / 8;
    liepe_mfma<<<nwg, 256, 0, stream>>>(x, r, wsA, out, n_tokens);
}

// Round 8
// 47.896 us; speedup vs baseline: 1.0004x; 1.0004x over previous
//
#include <hip/hip_runtime.h>

// ExplicitLiePE via MFMA: y[b,s] = expm(A) @ x[b,s], A = sum_k r_k * 0.5*(L_k - L_k^T).
//
// Round-6 (16-token groups, 4 waves/block row-split): 27us main at 2 waves/SIMD,
// ~60% latency stall on the per-step serial chain (renorm -> pkrtz -> ds_write
// -> barrier -> ds_read -> MFMA -> update).
// Round-7 (8-token groups, 4 blocks/CU): REGRESSED 46us -- amdgpu_waves_per_eu(4)
// sets only a MINIMUM; the allocator targeted 8 waves/SIMD, VGPR=64, spilling
// A-fragments + state to (L2-resident) scratch: no FETCH explosion, but every
// step reloaded 12 A-frags via VMEM.
//
// Round-8: same structure, amdgpu_waves_per_eu(4, 4) -- BOTH bounds pinned.
// Allocator budget = 128 VGPR (demand ~110 -> no spill), scheduler target
// exactly 4 waves/SIMD. B columns 8..15 duplicate 0..7 (pure MFMA-pipe waste,
// which is ~13% utilized -> free); grid 1024 blocks -> 4 blocks/CU.
//
// Math (unchanged): 8 tokens/block advance in lockstep;
//   G_k = (L_k - L_k^T).B, t[:,c] = sum_k (r_k[c]/rho_c) G_k[:,c]
// via v_mfma_f32_16x16x32_f16 with f16 hi/lo split of both L' and b
// (Lhi.bhi + Lhi.blo + Llo.bhi, dropped term ~2^-24). Miller's unnormalized
// scale tamed by per-step renorm s = jc>1 ? rcp(jc) : 1 (result is
// scale-invariant). Per-token seeding at m==ms, coeff gated by m<=M.
//
// Layouts:
//  - C/D: reg r of lane l = D[16*w + (l>>4)*4 + r][l&15] (HW-verified m89/m91).
//  - A/B k-slot bijection k = 8*(l>>4)+j within each K=32 tile.
//  - staging: stage[buf][hi/lo][token ct][dword]; token stride 36 dwords.

typedef _Float16 half8 __attribute__((ext_vector_type(8)));
typedef __fp16 fp16x2 __attribute__((ext_vector_type(2)));
typedef float float4t __attribute__((ext_vector_type(4)));

union H2U { fp16x2 h; unsigned u; };

__device__ __forceinline__ unsigned pkrtz2(float a, float b) {
    H2U v; v.h = __builtin_amdgcn_cvt_pkrtz(a, b); return v.u;
}
__device__ __forceinline__ float h2lo(unsigned u) { H2U v; v.u = u; return (float)v.h[0]; }
__device__ __forceinline__ float h2hi(unsigned u) { H2U v; v.u = u; return (float)v.h[1]; }

// ---------------- prepass: skew-symmetrize + f16 hi/lo split into fragments ----
// ws layout (f16): hi at [f*512 + l*8 + j], lo at +12288, f = (gen*4+m2)*2+kt.
// Fragment element (l, j) of tile (gen, m2, kt) = L'[16m2 + (l&15)][32kt + 8*(l>>4) + j].
__global__ void liepe_prep(const float* __restrict__ L, _Float16* __restrict__ wsA)
{
    int t = blockIdx.x * 256 + threadIdx.x;
    if (t >= 1536) return;
    int l   = t & 63;
    int f   = t >> 6;
    int kt  = f & 1;
    int m   = (f >> 1) & 3;
    int gen = f >> 3;
    int i   = 16 * m + (l & 15);
    int kk0 = 32 * kt + 8 * (l >> 4);
    const float* Lg = L + gen * 4096;
    half8 hi, lo;
    #pragma unroll
    for (int j = 0; j < 8; ++j) {
        int kk = kk0 + j;
        float d = Lg[i * 64 + kk] - Lg[kk * 64 + i];
        _Float16 h = (_Float16)d;
        hi[j] = h;
        lo[j] = (_Float16)(d - (float)h);
    }
    *(half8*)(wsA + f * 512 + l * 8) = hi;
    *(half8*)(wsA + 12288 + f * 512 + l * 8) = lo;
}

// ---------------- main kernel: 4 waves per block, 8 tokens per block ---------

#define PSTR 36   // token stride in dwords (b128-aligned reads)

// stage own b1 slice (hi/lo f16, lanes c<8 only), sync, load B frags, flip buf.
#define STAGE_AND_LOAD_B()                                                       \
  {                                                                              \
    if (c < 8) {                                                                 \
      unsigned h0 = pkrtz2(b1[0], b1[1]);                                        \
      unsigned h1 = pkrtz2(b1[2], b1[3]);                                        \
      unsigned l0 = pkrtz2(b1[0] - h2lo(h0), b1[1] - h2hi(h0));                  \
      unsigned l1 = pkrtz2(b1[2] - h2lo(h1), b1[3] - h2hi(h1));                  \
      const int di = 8 * w + 2 * g;                                              \
      *(uint2*)&stage[buf][0][c][di] = make_uint2(h0, h1);                       \
      *(uint2*)&stage[buf][1][c][di] = make_uint2(l0, l1);                       \
    }                                                                            \
    __syncthreads();                                                             \
    _Pragma("unroll")                                                            \
    for (int kt = 0; kt < 2; ++kt) {                                             \
      Bh[kt] = *(const half8*)&stage[buf][0][ct][16 * kt + 4 * g];               \
      Bl[kt] = *(const half8*)&stage[buf][1][ct][16 * kt + 4 * g];               \
    }                                                                            \
    buf ^= 1;                                                                    \
  }

// 18 MFMAs for this wave's 16-row tile; kt-split accumulators (6 short chains).
#define GEMM_COMBINE(TOUT)                                                       \
  {                                                                              \
    _Pragma("unroll")                                                            \
    for (int gen = 0; gen < 3; ++gen) {                                          \
      float q = (gen == 0) ? q0 : ((gen == 1) ? q1 : q2);                        \
      float4t ac0 = {0.f, 0.f, 0.f, 0.f};                                        \
      float4t ac1 = {0.f, 0.f, 0.f, 0.f};                                        \
      ac0 = __builtin_amdgcn_mfma_f32_16x16x32_f16(Ah[gen*2+0], Bh[0], ac0, 0, 0, 0); \
      ac1 = __builtin_amdgcn_mfma_f32_16x16x32_f16(Ah[gen*2+1], Bh[1], ac1, 0, 0, 0); \
      ac0 = __builtin_amdgcn_mfma_f32_16x16x32_f16(Ah[gen*2+0], Bl[0], ac0, 0, 0, 0); \
      ac1 = __builtin_amdgcn_mfma_f32_16x16x32_f16(Ah[gen*2+1], Bl[1], ac1, 0, 0, 0); \
      ac0 = __builtin_amdgcn_mfma_f32_16x16x32_f16(Al[gen*2+0], Bh[0], ac0, 0, 0, 0); \
      ac1 = __builtin_amdgcn_mfma_f32_16x16x32_f16(Al[gen*2+1], Bh[1], ac1, 0, 0, 0); \
      _Pragma("unroll")                                                          \
      for (int r4 = 0; r4 < 4; ++r4) {                                           \
        float sum = ac0[r4] + ac1[r4];                                           \
        if (gen == 0) TOUT[r4] = q * sum;                                        \
        else          TOUT[r4] = fmaf(q, sum, TOUT[r4]);                         \
      }                                                                          \
    }                                                                            \
  }

__global__ __launch_bounds__(256)
__attribute__((amdgpu_waves_per_eu(4, 4)))
void liepe_mfma(
    const float* __restrict__ x,
    const float* __restrict__ r_grid,
    const _Float16* __restrict__ wsA,
    float* __restrict__ out,
    int n_tokens)
{
    __shared__ __align__(16) unsigned stage[2][2][8][PSTR];  // 9.2KB

    const int lane = threadIdx.x & 63;
    const int w    = threadIdx.x >> 6;   // row-slice / m2 tile, 0..3
    const int c    = lane & 15;          // MFMA column of this lane
    const int ct   = c & 7;              // token index within group (col c and c+8 dup)
    const int g    = lane >> 4;          // k-group / row sub-block

    int tok = blockIdx.x * 8 + ct;
    if (tok >= n_tokens) tok = n_tokens - 1;

    // A-fragments for this wave's row slice (m2 = w): 6 hi + 6 lo (48 VGPRs).
    half8 Ah[6], Al[6];
    #pragma unroll
    for (int gen = 0; gen < 3; ++gen) {
        #pragma unroll
        for (int kt = 0; kt < 2; ++kt) {
            const int f = (gen * 4 + w) * 2 + kt;
            Ah[gen * 2 + kt] = *(const half8*)(wsA + f * 512 + lane * 8);
            Al[gen * 2 + kt] = *(const half8*)(wsA + 12288 + f * 512 + lane * 8);
        }
    }

    // x slice in D-layout: xv[r4] = x[tok][16w + 4g + r4].
    float xv[4];
    {
        float4 v = *(const float4*)(x + tok * 64 + 16 * w + 4 * g);
        xv[0] = v.x; xv[1] = v.y; xv[2] = v.z; xv[3] = v.w;
    }

    // Per-token scalars — identical in all 4 waves (and in lanes c, c+8).
    const float r0 = r_grid[tok * 3 + 0];
    const float r1 = r_grid[tok * 3 + 1];
    const float r2 = r_grid[tok * 3 + 2];
    const float sig2 = 0.5f * (r0 * r0 + r1 * r1 + r2 * r2);
    const float rho  = fmaf(17.3f, __builtin_sqrtf(sig2), 2.0f);
    const float inv_rho = 1.0f / rho;
    const int   M  = (int)rho + 14;     // >= ceil(rho)+13 -> tail ~1e-4
    const int   ms = M + 10;
    const float q0 = r0 * inv_rho, q1 = r1 * inv_rho, q2 = r2 * inv_rho;

    // block max degree (wave-reduce: every wave sees all group tokens).
    int maxM = M;
    #pragma unroll
    for (int off = 1; off < 64; off <<= 1)
        maxM = max(maxM, __shfl_xor(maxM, off));

    float jp = 0.f, jc = 0.f, N = 0.f;
    float b1[4] = {0.f, 0.f, 0.f, 0.f};
    float b2[4] = {0.f, 0.f, 0.f, 0.f};

    // ---- descent: Miller only (all b's exactly 0, no barriers needed) ----
    #pragma unroll 1
    for (int m = maxM + 10; m > maxM; --m) {
        bool sd = (m == ms);
        jc = sd ? 1e-12f : jc;
        jp = sd ? 0.f : jp;
        N  = sd ? (((m & 1) == 0) ? 2e-12f : 0.f) : N;
        float s = (jc > 1.0f) ? __builtin_amdgcn_rcpf(jc) : 1.0f;
        jc *= s; jp *= s; N *= s;
        float jm = fmaf((2.f * (float)m) * inv_rho, jc, -jp);
        jp = jc; jc = jm;
        int mm = m - 1;
        if ((mm & 1) == 0) N += (mm > 0) ? (jm + jm) : jm;
    }

    half8 Bh[2], Bl[2];
    int buf = 0;

    // ---- main fused Miller+Clenshaw loop (1 barrier per step, dbuf) ----
    #pragma unroll 1
    for (int m = maxM; m >= 1; --m) {
        bool sd = (m == ms);
        jc = sd ? 1e-12f : jc;
        jp = sd ? 0.f : jp;
        N  = sd ? (((m & 1) == 0) ? 2e-12f : 0.f) : N;

        // scale-invariant renorm: identical s across waves/dup-lanes
        float s = (jc > 1.0f) ? __builtin_amdgcn_rcpf(jc) : 1.0f;
        jc *= s; jp *= s; N *= s;
        #pragma unroll
        for (int i = 0; i < 4; ++i) { b1[i] *= s; b2[i] *= s; }

        STAGE_AND_LOAD_B();

        float t[4];
        GEMM_COMBINE(t);

        float cf = (m <= M) ? (jc + jc) : 0.f;
        #pragma unroll
        for (int i = 0; i < 4; ++i) {
            float bn = fmaf(cf, xv[i], t[i] + b2[i]);
            b2[i] = b1[i];
            b1[i] = bn;
        }

        float jm = fmaf((2.f * (float)m) * inv_rho, jc, -jp);
        jp = jc; jc = jm;
        int mm = m - 1;
        if ((mm & 1) == 0) N += (mm > 0) ? (jm + jm) : jm;
    }

    // ---- final: b0 = J0*x + (2A/rho)b1 + b2;  y = (b0 - 0.5*(2A/rho)b1)/N ----
    {
        STAGE_AND_LOAD_B();
        float t[4];
        GEMM_COMBINE(t);
        float4 v;
        float y0 = fmaf(jc, xv[0], t[0] + b2[0]);
        float y1 = fmaf(jc, xv[1], t[1] + b2[1]);
        float y2 = fmaf(jc, xv[2], t[2] + b2[2]);
        float y3 = fmaf(jc, xv[3], t[3] + b2[3]);
        v.x = (y0 - 0.5f * t[0]) / N;
        v.y = (y1 - 0.5f * t[1]) / N;
        v.z = (y2 - 0.5f * t[2]) / N;
        v.w = (y3 - 0.5f * t[3]) / N;
        if (c < 8) *(float4*)(out + tok * 64 + 16 * w + 4 * g) = v;
    }
}

extern "C" void kernel_launch(void* const* d_in, const int* in_sizes, int n_in,
                              void* d_out, int out_size, void* d_ws, size_t ws_size,
                              hipStream_t stream) {
    const float* x = (const float*)d_in[0];
    const float* r = (const float*)d_in[1];
    const float* L = (const float*)d_in[2];
    // d_in[3] = P_sp: identity (allow_mixing=False) -> R_eff = R_r.
    float* out = (float*)d_out;
    _Float16* wsA = (_Float16*)d_ws;   // 48KB: 24 hi + 24 lo fragments

    int n_tokens = in_sizes[0] / 64;   // B*S = 8192

    liepe_prep<<<6, 256, 0, stream>>>(L, wsA);

    int nwg = (n_tokens + 7) / 8;
    liepe_mfma<<<nwg, 256, 0, stream>>>(x, r, wsA, out, n_tokens);
}

// Round 9
// 37.662 us; speedup vs baseline: 1.2722x; 1.2718x over previous
//
#include <hip/hip_runtime.h>

// ExplicitLiePE via MFMA: y[b,s] = expm(A) @ x[b,s], A = sum_k r_k * 0.5*(L_k - L_k^T).
//
// Ladder: r5 MFMA 1-wave/16tok = 42us (latency-bound, half the SIMDs empty).
// r6 row-split 4 waves/block = 27us main (574ns/step vs ~67ns issue: serial
// chain stage->barrier->ds_read->MFMA->update ~1400cy, partially overlapped).
// r7/r8 column-duplication for occupancy REGRESSED (46us): doubled VALU+MFMA
// per token; phase-locked waves hid little. Lesson: never buy occupancy with
// duplicated work.
//
// Round-9: r6 structure + TWO INDEPENDENT 16-token groups per block (32/block,
// 256 blocks ~ 1/CU). A-fragments shared (same generators -> no duplicated
// work); per-group staging buffers + Clenshaw/Miller state. Per step: stage
// G0, stage G1, ONE barrier, then read+GEMM+update of G0 and G1 interleave --
// two independent chains fill each other's ds_read/MFMA latency in-wave
// (the verified round-2 trick, applied at the MFMA structure).
// Per-token arithmetic bit-identical to r6 -> absmax exactly 0.015625.
//
// Register control (r1/r7/r8 lessons): amdgpu_waves_per_eu(1,2) -- min=1 keeps
// the allocator budget at 512 VGPRs (demand ~180 -> no spill-for-occupancy),
// max=2 caps the scheduler target.
//
// Math per group (unchanged): 16 tokens lockstep;
//   G_k = (L_k - L_k^T).B, t[:,c] = sum_k (r_k[c]/rho_c) G_k[:,c]
// via v_mfma_f32_16x16x32_f16, f16 hi/lo split of both L' and b
// (Lhi.bhi + Lhi.blo + Llo.bhi; dropped term ~2^-24). Miller's growth tamed by
// per-step renorm s = jc>1 ? rcp(jc) : 1 (result scale-invariant). Per-token
// seeding at m==ms, coeff gated by m<=M.
//
// Layouts:
//  - C/D: reg r of lane l = D[16*w + (l>>4)*4 + r][l&15] (HW-verified m89/m91).
//  - A/B k-slot bijection k = 8*(l>>4)+j within each K=32 tile.
//  - staging: stage[group][buf][hi/lo][token c][dword], token stride 36 dwords.

typedef _Float16 half8 __attribute__((ext_vector_type(8)));
typedef __fp16 fp16x2 __attribute__((ext_vector_type(2)));
typedef float float4t __attribute__((ext_vector_type(4)));

union H2U { fp16x2 h; unsigned u; };

__device__ __forceinline__ unsigned pkrtz2(float a, float b) {
    H2U v; v.h = __builtin_amdgcn_cvt_pkrtz(a, b); return v.u;
}
__device__ __forceinline__ float h2lo(unsigned u) { H2U v; v.u = u; return (float)v.h[0]; }
__device__ __forceinline__ float h2hi(unsigned u) { H2U v; v.u = u; return (float)v.h[1]; }

// ---------------- prepass: skew-symmetrize + f16 hi/lo split into fragments ----
// ws layout (f16): hi at [f*512 + l*8 + j], lo at +12288, f = (gen*4+m2)*2+kt.
// Fragment element (l, j) of tile (gen, m2, kt) = L'[16m2 + (l&15)][32kt + 8*(l>>4) + j].
__global__ void liepe_prep(const float* __restrict__ L, _Float16* __restrict__ wsA)
{
    int t = blockIdx.x * 256 + threadIdx.x;
    if (t >= 1536) return;
    int l   = t & 63;
    int f   = t >> 6;
    int kt  = f & 1;
    int m   = (f >> 1) & 3;
    int gen = f >> 3;
    int i   = 16 * m + (l & 15);
    int kk0 = 32 * kt + 8 * (l >> 4);
    const float* Lg = L + gen * 4096;
    half8 hi, lo;
    #pragma unroll
    for (int j = 0; j < 8; ++j) {
        int kk = kk0 + j;
        float d = Lg[i * 64 + kk] - Lg[kk * 64 + i];
        _Float16 h = (_Float16)d;
        hi[j] = h;
        lo[j] = (_Float16)(d - (float)h);
    }
    *(half8*)(wsA + f * 512 + l * 8) = hi;
    *(half8*)(wsA + 12288 + f * 512 + l * 8) = lo;
}

// -------- main kernel: 4 waves per block, 2 groups x 16 tokens per block -----

#define PSTR 36   // token stride in dwords (b128-aligned reads)

#define STAGE_B(G, B1)                                                        \
  {                                                                           \
    unsigned h0 = pkrtz2(B1[0], B1[1]);                                       \
    unsigned h1 = pkrtz2(B1[2], B1[3]);                                       \
    unsigned l0 = pkrtz2(B1[0] - h2lo(h0), B1[1] - h2hi(h0));                 \
    unsigned l1 = pkrtz2(B1[2] - h2lo(h1), B1[3] - h2hi(h1));                 \
    const int di = 8 * w + 2 * g;                                             \
    *(uint2*)&stage[G][buf][0][c][di] = make_uint2(h0, h1);                   \
    *(uint2*)&stage[G][buf][1][c][di] = make_uint2(l0, l1);                   \
  }

#define LOAD_B(G, BH, BL)                                                     \
  {                                                                           \
    _Pragma("unroll")                                                         \
    for (int kt = 0; kt < 2; ++kt) {                                          \
      BH[kt] = *(const half8*)&stage[G][buf][0][c][16 * kt + 4 * g];          \
      BL[kt] = *(const half8*)&stage[G][buf][1][c][16 * kt + 4 * g];          \
    }                                                                         \
  }

// 18 MFMAs for this wave's 16-row tile; kt-split accumulators (6 chains of 3).
#define GEMM_COMBINE(BH, BL, Q0, Q1, Q2, TOUT)                                \
  {                                                                           \
    _Pragma("unroll")                                                         \
    for (int gen = 0; gen < 3; ++gen) {                                       \
      float q = (gen == 0) ? Q0 : ((gen == 1) ? Q1 : Q2);                     \
      float4t ac0 = {0.f, 0.f, 0.f, 0.f};                                     \
      float4t ac1 = {0.f, 0.f, 0.f, 0.f};                                     \
      ac0 = __builtin_amdgcn_mfma_f32_16x16x32_f16(Ah[gen*2+0], BH[0], ac0, 0, 0, 0); \
      ac1 = __builtin_amdgcn_mfma_f32_16x16x32_f16(Ah[gen*2+1], BH[1], ac1, 0, 0, 0); \
      ac0 = __builtin_amdgcn_mfma_f32_16x16x32_f16(Ah[gen*2+0], BL[0], ac0, 0, 0, 0); \
      ac1 = __builtin_amdgcn_mfma_f32_16x16x32_f16(Ah[gen*2+1], BL[1], ac1, 0, 0, 0); \
      ac0 = __builtin_amdgcn_mfma_f32_16x16x32_f16(Al[gen*2+0], BH[0], ac0, 0, 0, 0); \
      ac1 = __builtin_amdgcn_mfma_f32_16x16x32_f16(Al[gen*2+1], BH[1], ac1, 0, 0, 0); \
      _Pragma("unroll")                                                       \
      for (int r4 = 0; r4 < 4; ++r4) {                                        \
        float sum = ac0[r4] + ac1[r4];                                        \
        if (gen == 0) TOUT[r4] = q * sum;                                     \
        else          TOUT[r4] = fmaf(q, sum, TOUT[r4]);                      \
      }                                                                       \
    }                                                                         \
  }

// Miller/renorm scalar phases, per group (suffix-expanded: no runtime indexing).
#define SCALAR_PRE(S)                                                         \
  { bool sd = (m == ms##S);                                                   \
    jc##S = sd ? 1e-12f : jc##S;                                              \
    jp##S = sd ? 0.f : jp##S;                                                 \
    N##S  = sd ? (((m & 1) == 0) ? 2e-12f : 0.f) : N##S;                      \
    float s = (jc##S > 1.0f) ? __builtin_amdgcn_rcpf(jc##S) : 1.0f;           \
    jc##S *= s; jp##S *= s; N##S *= s;                                        \
    _Pragma("unroll")                                                         \
    for (int i = 0; i < 4; ++i) { b1##S[i] *= s; b2##S[i] *= s; } }

#define SCALAR_POST(S, T)                                                     \
  { float cf = (m <= M##S) ? (jc##S + jc##S) : 0.f;                           \
    _Pragma("unroll")                                                         \
    for (int i = 0; i < 4; ++i) {                                             \
      float bn = fmaf(cf, xv##S[i], T[i] + b2##S[i]);                         \
      b2##S[i] = b1##S[i]; b1##S[i] = bn; }                                   \
    float jm = fmaf((2.f * (float)m) * inv##S, jc##S, -jp##S);                \
    jp##S = jc##S; jc##S = jm;                                                \
    int mm = m - 1;                                                           \
    if ((mm & 1) == 0) N##S += (mm > 0) ? (jm + jm) : jm; }

#define MILLER_DESC(S)                                                        \
  { bool sd = (m == ms##S);                                                   \
    jc##S = sd ? 1e-12f : jc##S;                                              \
    jp##S = sd ? 0.f : jp##S;                                                 \
    N##S  = sd ? (((m & 1) == 0) ? 2e-12f : 0.f) : N##S;                      \
    float s = (jc##S > 1.0f) ? __builtin_amdgcn_rcpf(jc##S) : 1.0f;           \
    jc##S *= s; jp##S *= s; N##S *= s;                                        \
    float jm = fmaf((2.f * (float)m) * inv##S, jc##S, -jp##S);                \
    jp##S = jc##S; jc##S = jm;                                                \
    int mm = m - 1;                                                           \
    if ((mm & 1) == 0) N##S += (mm > 0) ? (jm + jm) : jm; }

#define INIT_GROUP(S, TOK)                                                    \
    float xv##S[4];                                                           \
    {                                                                         \
        float4 v = *(const float4*)(x + (TOK) * 64 + 16 * w + 4 * g);         \
        xv##S[0] = v.x; xv##S[1] = v.y; xv##S[2] = v.z; xv##S[3] = v.w;       \
    }                                                                         \
    const float r0##S = r_grid[(TOK) * 3 + 0];                                \
    const float r1##S = r_grid[(TOK) * 3 + 1];                                \
    const float r2##S = r_grid[(TOK) * 3 + 2];                                \
    const float sig##S = 0.5f * (r0##S*r0##S + r1##S*r1##S + r2##S*r2##S);    \
    const float rho##S = fmaf(17.3f, __builtin_sqrtf(sig##S), 2.0f);          \
    const float inv##S = 1.0f / rho##S;                                       \
    const int   M##S   = (int)rho##S + 14;                                    \
    const int   ms##S  = M##S + 10;                                           \
    const float q0##S = r0##S * inv##S;                                       \
    const float q1##S = r1##S * inv##S;                                       \
    const float q2##S = r2##S * inv##S;                                       \
    float jp##S = 0.f, jc##S = 0.f, N##S = 0.f;                               \
    float b1##S[4] = {0.f, 0.f, 0.f, 0.f};                                    \
    float b2##S[4] = {0.f, 0.f, 0.f, 0.f};

__global__ __launch_bounds__(256)
__attribute__((amdgpu_waves_per_eu(1, 2)))
void liepe_mfma(
    const float* __restrict__ x,
    const float* __restrict__ r_grid,
    const _Float16* __restrict__ wsA,
    float* __restrict__ out,
    int n_tokens)
{
    __shared__ __align__(16) unsigned stage[2][2][2][16][PSTR];  // 36KB

    const int lane = threadIdx.x & 63;
    const int w    = threadIdx.x >> 6;   // row-slice / m2 tile, 0..3
    const int c    = lane & 15;          // token column
    const int g    = lane >> 4;          // k-group / row sub-block

    int tok0 = blockIdx.x * 32 + c;
    int tok1 = blockIdx.x * 32 + 16 + c;
    if (tok0 >= n_tokens) tok0 = n_tokens - 1;
    if (tok1 >= n_tokens) tok1 = n_tokens - 1;

    // Shared A-fragments for this wave's row slice (m2 = w): 6 hi + 6 lo.
    half8 Ah[6], Al[6];
    #pragma unroll
    for (int gen = 0; gen < 3; ++gen) {
        #pragma unroll
        for (int kt = 0; kt < 2; ++kt) {
            const int f = (gen * 4 + w) * 2 + kt;
            Ah[gen * 2 + kt] = *(const half8*)(wsA + f * 512 + lane * 8);
            Al[gen * 2 + kt] = *(const half8*)(wsA + 12288 + f * 512 + lane * 8);
        }
    }

    INIT_GROUP(A, tok0)
    INIT_GROUP(B, tok1)

    // block max degree over BOTH groups (wave-reduce: lanes span all tokens).
    int maxM = (MA > MB) ? MA : MB;
    #pragma unroll
    for (int off = 1; off < 64; off <<= 1)
        maxM = max(maxM, __shfl_xor(maxM, off));

    // ---- descent: Miller only (all b's exactly 0, no barriers needed) ----
    #pragma unroll 1
    for (int m = maxM + 10; m > maxM; --m) {
        MILLER_DESC(A)
        MILLER_DESC(B)
    }

    half8 BhA[2], BlA[2], BhB[2], BlB[2];
    int buf = 0;

    // ---- main fused Miller+Clenshaw loop: two independent chains per wave ----
    #pragma unroll 1
    for (int m = maxM; m >= 1; --m) {
        SCALAR_PRE(A)
        SCALAR_PRE(B)

        STAGE_B(0, b1A)
        STAGE_B(1, b1B)
        __syncthreads();
        LOAD_B(0, BhA, BlA)
        LOAD_B(1, BhB, BlB)

        float tA[4], tB[4];
        GEMM_COMBINE(BhA, BlA, q0A, q1A, q2A, tA)
        GEMM_COMBINE(BhB, BlB, q0B, q1B, q2B, tB)

        SCALAR_POST(A, tA)
        SCALAR_POST(B, tB)
        buf ^= 1;
    }

    // ---- final: b0 = J0*x + (2A/rho)b1 + b2;  y = (b0 - 0.5*(2A/rho)b1)/N ----
    {
        STAGE_B(0, b1A)
        STAGE_B(1, b1B)
        __syncthreads();
        LOAD_B(0, BhA, BlA)
        LOAD_B(1, BhB, BlB)

        float tA[4], tB[4];
        GEMM_COMBINE(BhA, BlA, q0A, q1A, q2A, tA)
        GEMM_COMBINE(BhB, BlB, q0B, q1B, q2B, tB)

        float4 v;
        v.x = (fmaf(jcA, xvA[0], tA[0] + b2A[0]) - 0.5f * tA[0]) / NA;
        v.y = (fmaf(jcA, xvA[1], tA[1] + b2A[1]) - 0.5f * tA[1]) / NA;
        v.z = (fmaf(jcA, xvA[2], tA[2] + b2A[2]) - 0.5f * tA[2]) / NA;
        v.w = (fmaf(jcA, xvA[3], tA[3] + b2A[3]) - 0.5f * tA[3]) / NA;
        *(float4*)(out + tok0 * 64 + 16 * w + 4 * g) = v;

        float4 u;
        u.x = (fmaf(jcB, xvB[0], tB[0] + b2B[0]) - 0.5f * tB[0]) / NB;
        u.y = (fmaf(jcB, xvB[1], tB[1] + b2B[1]) - 0.5f * tB[1]) / NB;
        u.z = (fmaf(jcB, xvB[2], tB[2] + b2B[2]) - 0.5f * tB[2]) / NB;
        u.w = (fmaf(jcB, xvB[3], tB[3] + b2B[3]) - 0.5f * tB[3]) / NB;
        *(float4*)(out + tok1 * 64 + 16 * w + 4 * g) = u;
    }
}

extern "C" void kernel_launch(void* const* d_in, const int* in_sizes, int n_in,
                              void* d_out, int out_size, void* d_ws, size_t ws_size,
                              hipStream_t stream) {
    const float* x = (const float*)d_in[0];
    const float* r = (const float*)d_in[1];
    const float* L = (const float*)d_in[2];
    // d_in[3] = P_sp: identity (allow_mixing=False) -> R_eff = R_r.
    float* out = (float*)d_out;
    _Float16* wsA = (_Float16*)d_ws;   // 48KB: 24 hi + 24 lo fragments

    int n_tokens = in_sizes[0] / 64;   // B*S = 8192

    liepe_prep<<<6, 256, 0, stream>>>(L, wsA);

    int nwg = (n_tokens + 31) / 32;
    liepe_mfma<<<nwg, 256, 0, stream>>>(x, r, wsA, out, n_tokens);
}